// Round 7
// baseline (77.020 us; speedup 1.0000x reference)
//
#include <hip/hip_runtime.h>

// MHAGRU, 2 kernels: [input_proj + GRU scan] -> [MHA (2 pairs / 4 waves per block) || out_proj].
// B=32 T=64 F=128 H=8 NH=4 HD=2 HID=32. All f32.
// d_out = [ y (B*T*HID) | attention (B*T*F*H) ]
// d_ws  = [ out (B*F*T*H) ]
//
// R7: MHA wave-density doubled (8 waves/SIMD nominal) and per-wave serial C2
// halved: block = 2 pairs x 4 waves; waves 0/1 do C1/C3 for their pair, all 4
// waves split C2 (2 q-row-groups each). LDS 14.3KB/block.

namespace {
constexpr int Bb = 32, Tt = 64, Ff = 128, Hh = 8, HIDh = 32;
constexpr int G3H = 24;
constexpr float L2E = 1.44269504088896340736f;
// k_gruproj LDS (floats):
constexpr int XS_STRIDE = 130;
constexpr int XP_OFF = Tt * XS_STRIDE;     // 8320
constexpr int SMEM_AB = XP_OFF + 8 * 65;   // 8840 floats = 35.4 KB
// k_mha per-pair LDS region (floats): kk0|kk1|vv0|vv1 ([4][68]) + q/ctx [64][11]
constexpr int KK0 = 0, KK1 = 272, VV0 = 544, VV1 = 816, QS = 1088;
constexpr int PREG = 1792;                 // floats per pair; x2 pairs = 14336 B
}

__device__ __forceinline__ float rcp_(float x) {
#if __has_builtin(__builtin_amdgcn_rcpf)
  return __builtin_amdgcn_rcpf(x);
#else
  return 1.0f / x;
#endif
}
__device__ __forceinline__ float exp2_(float x) {
#if __has_builtin(__builtin_amdgcn_exp2f)
  return __builtin_amdgcn_exp2f(x);
#else
  return exp2f(x);
#endif
}

// ---------------- K1: input_proj + per-feature GRU (R4's proven kernel) ----------------
__global__ __launch_bounds__(256) void k_gruproj(
    const float* __restrict__ x, const float* __restrict__ Wp, const float* __restrict__ bp,
    const float* __restrict__ W_ih, const float* __restrict__ b_ih,
    const float* __restrict__ W_hh, const float* __restrict__ b_hh,
    float* __restrict__ outp) {
  __shared__ float smem[SMEM_AB];
  const int tid = threadIdx.x;
  const int blk = blockIdx.x;
  const int b = blk >> 4;
  const int f0 = (blk & 15) * 8;
  const int lane = tid & 63;
  const int w = tid >> 6;

  {
    const float2* xb = (const float2*)(x + b * Tt * Ff);
    for (int i = tid; i < Tt * Ff / 2; i += 256) {
      int row = i >> 6, col2 = i & 63;
      *(float2*)&smem[row * XS_STRIDE + col2 * 2] = xb[i];
    }
  }
  __syncthreads();
  {
    const int t = lane;
    const int fA = f0 + w, fB = f0 + w + 4;
    float acc0 = bp[fA], acc1 = bp[fB];
    const float* wA = Wp + fA * Ff;
    const float* wB = Wp + fB * Ff;
    const float* xr = &smem[t * XS_STRIDE];
#pragma unroll 8
    for (int k = 0; k < Ff; k += 2) {
      float2 xv = *(const float2*)&xr[k];
      acc0 = fmaf(xv.x, wA[k], acc0); acc0 = fmaf(xv.y, wA[k + 1], acc0);
      acc1 = fmaf(xv.x, wB[k], acc1); acc1 = fmaf(xv.y, wB[k + 1], acc1);
    }
    smem[XP_OFF + w * 65 + t] = acc0;
    smem[XP_OFF + (w + 4) * 65 + t] = acc1;
  }
  __syncthreads();
  if (tid >= 64) return;

  {
    const int g = tid >> 3, j = tid & 7;
    const int f = f0 + g;
    const float* wb = W_hh + (f * G3H + j) * Hh;
    const float nL = -L2E, S2 = 2.0f * L2E;
    float w0s[8], w1s[8], w2s[8];
#pragma unroll
    for (int h = 0; h < 8; ++h) {
      w0s[h] = wb[h] * nL;
      w1s[h] = wb[64 + h] * nL;
      w2s[h] = wb[128 + h] * S2;
    }
    const float wi0s = W_ih[f * G3H + j] * nL;
    const float wi1s = W_ih[f * G3H + 8 + j] * nL;
    const float wi2s = W_ih[f * G3H + 16 + j] * S2;
    const float bias_r = (b_ih[f * G3H + j] + b_hh[f * G3H + j]) * nL;
    const float bias_z = (b_ih[f * G3H + 8 + j] + b_hh[f * G3H + 8 + j]) * nL;
    const float bi2s = b_ih[f * G3H + 16 + j] * S2;
    const float bh2s = b_hh[f * G3H + 16 + j] * S2;
    float hall[8];
#pragma unroll
    for (int h = 0; h < 8; ++h) hall[h] = 0.f;
    const int base = tid & 56;
    float* outb = outp + ((b * Ff + f) * Tt) * Hh + j;
    const float* xps = &smem[XP_OFF + g * 65];
    for (int t = 0; t < Tt; ++t) {
      float xt = xps[t];
      float a0 = bias_r, a1 = bias_z, a2 = bh2s;
#pragma unroll
      for (int h = 0; h < 8; ++h) {
        a0 = fmaf(hall[h], w0s[h], a0);
        a1 = fmaf(hall[h], w1s[h], a1);
        a2 = fmaf(hall[h], w2s[h], a2);
      }
      float r = rcp_(1.0f + exp2_(fmaf(xt, wi0s, a0)));
      float z = rcp_(1.0f + exp2_(fmaf(xt, wi1s, a1)));
      float narg = fmaf(r, a2, fmaf(xt, wi2s, bi2s));
      float n = fmaf(-2.0f, rcp_(exp2_(narg) + 1.0f), 1.0f);  // tanh
      float hn = fmaf(z, hall[j] - n, n);
      outb[t * Hh] = hn;
#pragma unroll
      for (int h = 0; h < 8; ++h) hall[h] = __shfl(hn, base + h, 64);
    }
  }
}

// 2-row softmax+PV step per kv component
#define MHA_STEP(K0C, K1C, V0C, V1C)                         \
  {                                                          \
    _Pragma("unroll") for (int i = 0; i < 2; ++i) {          \
      float s = fmaf(q0[i], K0C, q1[i] * K1C);               \
      float p = exp2_(s);                                    \
      ps[i] += p;                                            \
      c0[i] = fmaf(p, V0C, c0[i]);                           \
      c1[i] = fmaf(p, V1C, c1[i]);                           \
    }                                                        \
  }

// ---------------- K2: MHA (blocks 0..2047; 2 pairs per block) || out_proj ----------------
__global__ __launch_bounds__(256) void k_mha_outproj(
    const float* __restrict__ outp, const float* __restrict__ in_w,
    const float* __restrict__ in_b, const float* __restrict__ ow,
    const float* __restrict__ ob, const float* __restrict__ Wout,
    const float* __restrict__ bout, float* __restrict__ attn,
    float* __restrict__ y) {
  __shared__ float smem[2 * PREG];
  const int tid = threadIdx.x;
  if (blockIdx.x < 2048) {
    const int wv = tid >> 6;
    const int t = tid & 63;
    constexpr float SCL = 0.70710678118654752f * L2E;

    // ---- C1: waves 0/1 compute qkv for pair wv ----
    if (wv < 2) {
      const int pair = blockIdx.x * 2 + wv;
      float* sm = &smem[wv * PREG];
      const float4* src = (const float4*)(outp + pair * (Tt * Hh));
      float4 r0 = src[t * 2], r1 = src[t * 2 + 1];
      float sq[8] = {r0.x, r0.y, r0.z, r0.w, r1.x, r1.y, r1.z, r1.w};
      float qv[8], ka[8], va[8];
#pragma unroll
      for (int jj = 0; jj < 8; ++jj) {
        float aq = in_b[jj], ak = in_b[8 + jj], av = in_b[16 + jj];
#pragma unroll
        for (int h = 0; h < 8; ++h) {
          aq = fmaf(sq[h], in_w[jj * 8 + h], aq);
          ak = fmaf(sq[h], in_w[(8 + jj) * 8 + h], ak);
          av = fmaf(sq[h], in_w[(16 + jj) * 8 + h], av);
        }
        qv[jj] = aq * SCL; ka[jj] = ak; va[jj] = av;
      }
#pragma unroll
      for (int n = 0; n < 4; ++n) {
        *(float2*)&sm[QS + t * 11 + 2 * n] = make_float2(qv[2 * n], qv[2 * n + 1]);
        sm[KK0 + n * 68 + t] = ka[2 * n];
        sm[KK1 + n * 68 + t] = ka[2 * n + 1];
        sm[VV0 + n * 68 + t] = va[2 * n];
        sm[VV1 + n * 68 + t] = va[2 * n + 1];
      }
    }
    __syncthreads();

    // ---- C2: all 4 waves. wave (wv&1) -> pair, (wv>>1) -> row-half ----
    {
      float* sm = &smem[(wv & 1) * PREG];
      const int ihalf = (wv >> 1) * 2;       // i in {ihalf, ihalf+1}
      const int n = t >> 4, qq = t & 15;
      float q0[2], q1[2];
#pragma unroll
      for (int i = 0; i < 2; ++i) {
        float2 qp = *(const float2*)&sm[QS + (qq + 16 * (ihalf + i)) * 11 + 2 * n];
        q0[i] = qp.x; q1[i] = qp.y;
      }
      float ps[2], c0[2], c1[2];
#pragma unroll
      for (int i = 0; i < 2; ++i) { ps[i] = 0.f; c0[i] = 0.f; c1[i] = 0.f; }
#pragma unroll 4
      for (int kt4 = 0; kt4 < Tt; kt4 += 4) {
        float4 k0 = *(const float4*)&sm[KK0 + n * 68 + kt4];
        float4 k1 = *(const float4*)&sm[KK1 + n * 68 + kt4];
        float4 v0 = *(const float4*)&sm[VV0 + n * 68 + kt4];
        float4 v1 = *(const float4*)&sm[VV1 + n * 68 + kt4];
        MHA_STEP(k0.x, k1.x, v0.x, v1.x)
        MHA_STEP(k0.y, k1.y, v0.y, v1.y)
        MHA_STEP(k0.z, k1.z, v0.z, v1.z)
        MHA_STEP(k0.w, k1.w, v0.w, v1.w)
      }
#pragma unroll
      for (int i = 0; i < 2; ++i) {
        float inv = rcp_(ps[i]);
        *(float2*)&sm[QS + (qq + 16 * (ihalf + i)) * 11 + 2 * n] =
            make_float2(c0[i] * inv, c1[i] * inv);   // overwrite q with ctx
      }
    }
    __syncthreads();

    // ---- C3: waves 0/1 out_proj + store for pair wv ----
    if (wv < 2) {
      const int pair = blockIdx.x * 2 + wv;
      const int b = pair >> 7, f = pair & 127;
      float* sm = &smem[wv * PREG];
      float2 cp0 = *(const float2*)&sm[QS + t * 11 + 0];
      float2 cp1 = *(const float2*)&sm[QS + t * 11 + 2];
      float2 cp2 = *(const float2*)&sm[QS + t * 11 + 4];
      float2 cp3 = *(const float2*)&sm[QS + t * 11 + 6];
      float cx[8] = {cp0.x, cp0.y, cp1.x, cp1.y, cp2.x, cp2.y, cp3.x, cp3.y};
      float o8[8];
#pragma unroll
      for (int jj = 0; jj < 8; ++jj) {
        float a = ob[jj];
#pragma unroll
        for (int h = 0; h < 8; ++h) a = fmaf(cx[h], ow[jj * 8 + h], a);
        o8[jj] = a;
      }
      float4* dst = (float4*)(attn + ((b * Tt + t) * Ff + f) * Hh);
      dst[0] = make_float4(o8[0], o8[1], o8[2], o8[3]);
      dst[1] = make_float4(o8[4], o8[5], o8[6], o8[7]);
    }
  } else {
    // ===== out_proj: two independent 128-thread sub-units per block =====
    constexpr int TT = 8;
    const int sub = tid >> 7, stid = tid & 127;
    const int eblk = (blockIdx.x - 2048) * 2 + sub;   // 0..255
    const int b = eblk >> 3;
    const int t0 = (eblk & 7) * TT;
    const int oq = stid >> 4;
    const int fc = stid & 15;
    float acc[TT][4];
#pragma unroll
    for (int tt = 0; tt < TT; ++tt)
#pragma unroll
      for (int od = 0; od < 4; ++od) acc[tt][od] = 0.f;
#pragma unroll
    for (int ff = 0; ff < 8; ++ff) {
      int f = fc * 8 + ff;
      const float4* rb = (const float4*)(outp + ((b * Ff + f) * Tt + t0) * Hh);
      float4 rv[16];
#pragma unroll
      for (int i = 0; i < 16; ++i) rv[i] = rb[i];
#pragma unroll
      for (int od = 0; od < 4; ++od) {
        int o = oq * 4 + od;
        const float4* wbp = (const float4*)(Wout + o * (Ff * Hh) + f * Hh);
        float4 wa = wbp[0], wc = wbp[1];
#pragma unroll
        for (int tt = 0; tt < TT; ++tt) {
          float4 ra = rv[tt * 2], rc = rv[tt * 2 + 1];
          float s = acc[tt][od];
          s = fmaf(ra.x, wa.x, s); s = fmaf(ra.y, wa.y, s);
          s = fmaf(ra.z, wa.z, s); s = fmaf(ra.w, wa.w, s);
          s = fmaf(rc.x, wc.x, s); s = fmaf(rc.y, wc.y, s);
          s = fmaf(rc.z, wc.z, s); s = fmaf(rc.w, wc.w, s);
          acc[tt][od] = s;
        }
      }
    }
#pragma unroll
    for (int tt = 0; tt < TT; ++tt)
#pragma unroll
      for (int od = 0; od < 4; ++od) {
        float v = acc[tt][od];
        v += __shfl_xor(v, 1, 16);
        v += __shfl_xor(v, 2, 16);
        v += __shfl_xor(v, 4, 16);
        v += __shfl_xor(v, 8, 16);
        acc[tt][od] = v;
      }
#pragma unroll
    for (int tt = 0; tt < TT; ++tt) {
      if (fc == tt) {
#pragma unroll
        for (int od = 0; od < 4; ++od) {
          int o = oq * 4 + od;
          y[(b * Tt + t0 + tt) * HIDh + o] = acc[tt][od] + bout[o];
        }
      }
    }
  }
}

extern "C" void kernel_launch(void* const* d_in, const int* in_sizes, int n_in,
                              void* d_out, int out_size, void* d_ws, size_t ws_size,
                              hipStream_t stream) {
  (void)in_sizes; (void)n_in; (void)out_size; (void)ws_size;
  const float* x    = (const float*)d_in[0];
  const float* Wp   = (const float*)d_in[1];
  const float* bp   = (const float*)d_in[2];
  const float* W_ih = (const float*)d_in[3];
  const float* b_ih = (const float*)d_in[4];
  const float* W_hh = (const float*)d_in[5];
  const float* b_hh = (const float*)d_in[6];
  const float* in_w = (const float*)d_in[7];
  const float* in_b = (const float*)d_in[8];
  const float* ow   = (const float*)d_in[9];
  const float* ob   = (const float*)d_in[10];
  const float* Wout = (const float*)d_in[11];
  const float* bout = (const float*)d_in[12];

  float* y    = (float*)d_out;
  float* attn = (float*)d_out + Bb * Tt * HIDh;
  float* outp = (float*)d_ws;   // B*F*T*H

  hipLaunchKernelGGL(k_gruproj, dim3(Bb * (Ff / 8)), dim3(256), 0, stream,
                     x, Wp, bp, W_ih, b_ih, W_hh, b_hh, outp);
  hipLaunchKernelGGL(k_mha_outproj, dim3(2176), dim3(256), 0, stream,
                     outp, in_w, in_b, ow, ob, Wout, bout, attn, y);
}

// Round 8
// 65.484 us; speedup vs baseline: 1.1762x; 1.1762x over previous
//
#include <hip/hip_runtime.h>

// MHAGRU, 2 kernels: [input_proj + GRU scan] -> [MHA (wave-per-pair) || out_proj].
// B=32 T=64 F=128 H=8 NH=4 HD=2 HID=32. All f32.
// d_out = [ y (B*T*HID) | attention (B*T*F*H) ]
// d_ws  = [ out (B*F,T,H) ]
//
// R8: burst-store round. Theory: all previous MHA/GRU variants were HBM-write
// bound (32B/4B stores at 4KB/2KB stride -> partial-line evictions + DRAM row
// thrash; replays show 50us with FETCH~0 and only 8.6MB writes). Every global
// write is now a contiguous burst: GRU h-tile staged in LDS then streamed as
// 16KB-contiguous float4 stores; MHA attn staged in LDS then written as
// 128B-contiguous (4f x 8h) chunks per t.

namespace {
constexpr int Bb = 32, Tt = 64, Ff = 128, Hh = 8, HIDh = 32;
constexpr int G3H = 24;
constexpr float L2E = 1.44269504088896340736f;
// k_gruproj LDS (floats): [0:4160) hout (post-A, overlays xs) | [8320:8840) xp
constexpr int XS_STRIDE = 130;
constexpr int XP_OFF = Tt * XS_STRIDE;     // 8320
constexpr int SMEM_AB = XP_OFF + 8 * 65;   // 8840 floats = 35.4 KB
// k_mha per-wave LDS region (floats): kk0|kk1|vv0|vv1 ([4][68]) + q/ctx [64][10]
constexpr int KK0 = 0, KK1 = 272, VV0 = 544, VV1 = 816, QS = 1088;
constexpr int WREG = 1728;                 // floats per wave
constexpr int OCT = 4 * WREG;              // o8 staging: [4 pair][64 t][10]
constexpr int SMEM_MHA = OCT + 4 * 640;    // 9472 floats = 37.9 KB
}

__device__ __forceinline__ float rcp_(float x) {
#if __has_builtin(__builtin_amdgcn_rcpf)
  return __builtin_amdgcn_rcpf(x);
#else
  return 1.0f / x;
#endif
}
__device__ __forceinline__ float exp2_(float x) {
#if __has_builtin(__builtin_amdgcn_exp2f)
  return __builtin_amdgcn_exp2f(x);
#else
  return exp2f(x);
#endif
}

// ---------------- K1: input_proj + per-feature GRU, burst h-store ----------------
// grid: B*(F/8) = 512 blocks, 256 threads. Waves 1-3 retire after phase A.
__global__ __launch_bounds__(256) void k_gruproj(
    const float* __restrict__ x, const float* __restrict__ Wp, const float* __restrict__ bp,
    const float* __restrict__ W_ih, const float* __restrict__ b_ih,
    const float* __restrict__ W_hh, const float* __restrict__ b_hh,
    float* __restrict__ outp) {
  __shared__ float smem[SMEM_AB];
  const int tid = threadIdx.x;
  const int blk = blockIdx.x;
  const int b = blk >> 4;
  const int f0 = (blk & 15) * 8;
  const int lane = tid & 63;
  const int w = tid >> 6;

  // phase A: stage x[b] (64x128), compute xp for this block's 8 f's
  {
    const float2* xb = (const float2*)(x + b * Tt * Ff);
    for (int i = tid; i < Tt * Ff / 2; i += 256) {
      int row = i >> 6, col2 = i & 63;
      *(float2*)&smem[row * XS_STRIDE + col2 * 2] = xb[i];
    }
  }
  __syncthreads();
  {
    const int t = lane;
    const int fA = f0 + w, fB = f0 + w + 4;  // wave-uniform -> scalar Wp loads
    float acc0 = bp[fA], acc1 = bp[fB];
    const float* wA = Wp + fA * Ff;
    const float* wB = Wp + fB * Ff;
    const float* xr = &smem[t * XS_STRIDE];
#pragma unroll 8
    for (int k = 0; k < Ff; k += 2) {
      float2 xv = *(const float2*)&xr[k];
      acc0 = fmaf(xv.x, wA[k], acc0); acc0 = fmaf(xv.y, wA[k + 1], acc0);
      acc1 = fmaf(xv.x, wB[k], acc1); acc1 = fmaf(xv.y, wB[k + 1], acc1);
    }
    smem[XP_OFF + w * 65 + t] = acc0;
    smem[XP_OFF + (w + 4) * 65 + t] = acc1;
  }
  __syncthreads();
  if (tid >= 64) return;   // free 3/4 of the block's wave slots

  // phase B: GRU scan, lane = (g=f_local, j=hidden). h -> LDS (no global scatter).
  {
    const int g = tid >> 3, j = tid & 7;
    const int f = f0 + g;
    const float* wb = W_hh + (f * G3H + j) * Hh;
    const float nL = -L2E, S2 = 2.0f * L2E;
    float w0s[8], w1s[8], w2s[8];
#pragma unroll
    for (int h = 0; h < 8; ++h) {
      w0s[h] = wb[h] * nL;
      w1s[h] = wb[64 + h] * nL;
      w2s[h] = wb[128 + h] * S2;
    }
    const float wi0s = W_ih[f * G3H + j] * nL;
    const float wi1s = W_ih[f * G3H + 8 + j] * nL;
    const float wi2s = W_ih[f * G3H + 16 + j] * S2;
    const float bias_r = (b_ih[f * G3H + j] + b_hh[f * G3H + j]) * nL;
    const float bias_z = (b_ih[f * G3H + 8 + j] + b_hh[f * G3H + 8 + j]) * nL;
    const float bi2s = b_ih[f * G3H + 16 + j] * S2;
    const float bh2s = b_hh[f * G3H + 16 + j] * S2;
    float hall[8];
#pragma unroll
    for (int h = 0; h < 8; ++h) hall[h] = 0.f;
    const int base = tid & 56;
    float* hdst = &smem[g * 520 + j * 65];   // hout[g][j][t], banks (8g+j+t)%32: 2-way
    const float* xps = &smem[XP_OFF + g * 65];
    for (int t = 0; t < Tt; ++t) {
      float xt = xps[t];
      float a0 = bias_r, a1 = bias_z, a2 = bh2s;
#pragma unroll
      for (int h = 0; h < 8; ++h) {
        a0 = fmaf(hall[h], w0s[h], a0);
        a1 = fmaf(hall[h], w1s[h], a1);
        a2 = fmaf(hall[h], w2s[h], a2);
      }
      float r = rcp_(1.0f + exp2_(fmaf(xt, wi0s, a0)));
      float z = rcp_(1.0f + exp2_(fmaf(xt, wi1s, a1)));
      float narg = fmaf(r, a2, fmaf(xt, wi2s, bi2s));
      float n = fmaf(-2.0f, rcp_(exp2_(narg) + 1.0f), 1.0f);  // tanh
      float hn = fmaf(z, hall[j] - n, n);
      hdst[t] = hn;
#pragma unroll
      for (int h = 0; h < 8; ++h) hall[h] = __shfl(hn, base + h, 64);
    }
  }
  // burst store: 8f x 64t x 8j = 4096 floats = 16KB fully contiguous
  {
    float4* og = (float4*)(outp + (b * Ff + f0) * Tt * Hh);
#pragma unroll
    for (int i = 0; i < 16; ++i) {
      int v = i * 64 + tid;            // global float4 index within the tile
      int g = v >> 7;                  // f_local (128 float4 per f)
      int rem = v & 127;               // t*2 + jh
      int t = rem >> 1, j0 = (rem & 1) * 4;
      const float* hp = &smem[g * 520 + j0 * 65 + t];
      og[v] = make_float4(hp[0], hp[65], hp[130], hp[195]);
    }
  }
}

// 4-row softmax+PV step per kv component (R6 proven)
#define MHA_STEP(K0C, K1C, V0C, V1C)                         \
  {                                                          \
    _Pragma("unroll") for (int i = 0; i < 4; ++i) {          \
      float s = fmaf(q0[i], K0C, q1[i] * K1C);               \
      float p = exp2_(s);                                    \
      ps[i] += p;                                            \
      c0[i] = fmaf(p, V0C, c0[i]);                           \
      c1[i] = fmaf(p, V1C, c1[i]);                           \
    }                                                        \
  }

// ---------------- K2: MHA (blocks 0..1023; wave = (b,f) pair) || out_proj ----------------
__global__ __launch_bounds__(256) void k_mha_outproj(
    const float* __restrict__ outp, const float* __restrict__ in_w,
    const float* __restrict__ in_b, const float* __restrict__ ow,
    const float* __restrict__ ob, const float* __restrict__ Wout,
    const float* __restrict__ bout, float* __restrict__ attn,
    float* __restrict__ y) {
  __shared__ float smem[SMEM_MHA];
  const int tid = threadIdx.x;
  if (blockIdx.x < 1024) {
    // ===== MHA: one 64-lane wave per (b,f) pair; barrier-free until the store =====
    const int wv = tid >> 6;
    const int t = tid & 63;
    const int pair = blockIdx.x * 4 + wv;   // 4 consecutive f, same b
    float* sm = &smem[wv * WREG];

    // C1: qkv projection, lane = t
    const float4* src = (const float4*)(outp + pair * (Tt * Hh));
    float4 r0 = src[t * 2], r1 = src[t * 2 + 1];
    float sq[8] = {r0.x, r0.y, r0.z, r0.w, r1.x, r1.y, r1.z, r1.w};
    constexpr float SCL = 0.70710678118654752f * L2E;
    float qv[8], ka[8], va[8];
#pragma unroll
    for (int jj = 0; jj < 8; ++jj) {
      float aq = in_b[jj], ak = in_b[8 + jj], av = in_b[16 + jj];
#pragma unroll
      for (int h = 0; h < 8; ++h) {
        aq = fmaf(sq[h], in_w[jj * 8 + h], aq);
        ak = fmaf(sq[h], in_w[(8 + jj) * 8 + h], ak);
        av = fmaf(sq[h], in_w[(16 + jj) * 8 + h], av);
      }
      qv[jj] = aq * SCL; ka[jj] = ak; va[jj] = av;
    }
#pragma unroll
    for (int n = 0; n < 4; ++n) {
      *(float2*)&sm[QS + t * 10 + 2 * n] = make_float2(qv[2 * n], qv[2 * n + 1]);
      sm[KK0 + n * 68 + t] = ka[2 * n];
      sm[KK1 + n * 68 + t] = ka[2 * n + 1];
      sm[VV0 + n * 68 + t] = va[2 * n];
      sm[VV1 + n * 68 + t] = va[2 * n + 1];
    }
    asm volatile("s_waitcnt lgkmcnt(0)" ::: "memory");  // within-wave RAW

    // C2: lane = (n = t>>4, qq = t&15); 4 q-rows x 1 head
    const int n = t >> 4, qq = t & 15;
    float q0[4], q1[4];
#pragma unroll
    for (int i = 0; i < 4; ++i) {
      float2 qp = *(const float2*)&sm[QS + (qq + 16 * i) * 10 + 2 * n];
      q0[i] = qp.x; q1[i] = qp.y;
    }
    float ps[4], c0[4], c1[4];
#pragma unroll
    for (int i = 0; i < 4; ++i) { ps[i] = 0.f; c0[i] = 0.f; c1[i] = 0.f; }
#pragma unroll 2
    for (int kt4 = 0; kt4 < Tt; kt4 += 4) {
      float4 k0 = *(const float4*)&sm[KK0 + n * 68 + kt4];
      float4 k1 = *(const float4*)&sm[KK1 + n * 68 + kt4];
      float4 v0 = *(const float4*)&sm[VV0 + n * 68 + kt4];
      float4 v1 = *(const float4*)&sm[VV1 + n * 68 + kt4];
      MHA_STEP(k0.x, k1.x, v0.x, v1.x)
      MHA_STEP(k0.y, k1.y, v0.y, v1.y)
      MHA_STEP(k0.z, k1.z, v0.z, v1.z)
      MHA_STEP(k0.w, k1.w, v0.w, v1.w)
    }
#pragma unroll
    for (int i = 0; i < 4; ++i) {
      float inv = rcp_(ps[i]);
      *(float2*)&sm[QS + (qq + 16 * i) * 10 + 2 * n] =
          make_float2(c0[i] * inv, c1[i] * inv);   // overwrite q with ctx
    }
    asm volatile("s_waitcnt lgkmcnt(0)" ::: "memory");

    // C3: lane = t; out_proj of ctx row t -> stage o8 in LDS (no scatter store)
    {
      float2 cp0 = *(const float2*)&sm[QS + t * 10 + 0];
      float2 cp1 = *(const float2*)&sm[QS + t * 10 + 2];
      float2 cp2 = *(const float2*)&sm[QS + t * 10 + 4];
      float2 cp3 = *(const float2*)&sm[QS + t * 10 + 6];
      float cx[8] = {cp0.x, cp0.y, cp1.x, cp1.y, cp2.x, cp2.y, cp3.x, cp3.y};
      float o8[8];
#pragma unroll
      for (int jj = 0; jj < 8; ++jj) {
        float a = ob[jj];
#pragma unroll
        for (int h = 0; h < 8; ++h) a = fmaf(cx[h], ow[jj * 8 + h], a);
        o8[jj] = a;
      }
      float* od = &smem[OCT + wv * 640 + t * 10];
      *(float4*)&od[0] = make_float4(o8[0], o8[1], o8[2], o8[3]);
      *(float4*)&od[4] = make_float4(o8[4], o8[5], o8[6], o8[7]);
    }
    __syncthreads();

    // burst store: per t, 4 consecutive f x 8h = 128B contiguous (full L2 lines)
    {
      const int bt = tid >> 2;          // t
      const int c = tid & 3;            // f_local
      const int b = blockIdx.x >> 5;
      const int f0 = (blockIdx.x & 31) * 4;
      const float* sp = &smem[OCT + c * 640 + bt * 10];
      float4* dst = (float4*)(attn + ((b * Tt + bt) * Ff + f0 + c) * Hh);
      dst[0] = *(const float4*)&sp[0];
      dst[1] = *(const float4*)&sp[4];
    }
  } else {
    // ===== out_proj: two independent 128-thread sub-units per block =====
    constexpr int TT = 8;
    const int sub = tid >> 7, stid = tid & 127;
    const int eblk = (blockIdx.x - 1024) * 2 + sub;   // 0..255
    const int b = eblk >> 3;
    const int t0 = (eblk & 7) * TT;
    const int oq = stid >> 4;
    const int fc = stid & 15;
    float acc[TT][4];
#pragma unroll
    for (int tt = 0; tt < TT; ++tt)
#pragma unroll
      for (int od = 0; od < 4; ++od) acc[tt][od] = 0.f;
#pragma unroll
    for (int ff = 0; ff < 8; ++ff) {
      int f = fc * 8 + ff;
      const float4* rb = (const float4*)(outp + ((b * Ff + f) * Tt + t0) * Hh);
      float4 rv[16];
#pragma unroll
      for (int i = 0; i < 16; ++i) rv[i] = rb[i];
#pragma unroll
      for (int od = 0; od < 4; ++od) {
        int o = oq * 4 + od;
        const float4* wbp = (const float4*)(Wout + o * (Ff * Hh) + f * Hh);
        float4 wa = wbp[0], wc = wbp[1];
#pragma unroll
        for (int tt = 0; tt < TT; ++tt) {
          float4 ra = rv[tt * 2], rc = rv[tt * 2 + 1];
          float s = acc[tt][od];
          s = fmaf(ra.x, wa.x, s); s = fmaf(ra.y, wa.y, s);
          s = fmaf(ra.z, wa.z, s); s = fmaf(ra.w, wa.w, s);
          s = fmaf(rc.x, wc.x, s); s = fmaf(rc.y, wc.y, s);
          s = fmaf(rc.z, wc.z, s); s = fmaf(rc.w, wc.w, s);
          acc[tt][od] = s;
        }
      }
    }
#pragma unroll
    for (int tt = 0; tt < TT; ++tt)
#pragma unroll
      for (int od = 0; od < 4; ++od) {
        float v = acc[tt][od];
        v += __shfl_xor(v, 1, 16);
        v += __shfl_xor(v, 2, 16);
        v += __shfl_xor(v, 4, 16);
        v += __shfl_xor(v, 8, 16);
        acc[tt][od] = v;
      }
#pragma unroll
    for (int tt = 0; tt < TT; ++tt) {
      if (fc == tt) {
#pragma unroll
        for (int od = 0; od < 4; ++od) {
          int o = oq * 4 + od;
          y[(b * Tt + t0 + tt) * HIDh + o] = acc[tt][od] + bout[o];
        }
      }
    }
  }
}

extern "C" void kernel_launch(void* const* d_in, const int* in_sizes, int n_in,
                              void* d_out, int out_size, void* d_ws, size_t ws_size,
                              hipStream_t stream) {
  (void)in_sizes; (void)n_in; (void)out_size; (void)ws_size;
  const float* x    = (const float*)d_in[0];
  const float* Wp   = (const float*)d_in[1];
  const float* bp   = (const float*)d_in[2];
  const float* W_ih = (const float*)d_in[3];
  const float* b_ih = (const float*)d_in[4];
  const float* W_hh = (const float*)d_in[5];
  const float* b_hh = (const float*)d_in[6];
  const float* in_w = (const float*)d_in[7];
  const float* in_b = (const float*)d_in[8];
  const float* ow   = (const float*)d_in[9];
  const float* ob   = (const float*)d_in[10];
  const float* Wout = (const float*)d_in[11];
  const float* bout = (const float*)d_in[12];

  float* y    = (float*)d_out;
  float* attn = (float*)d_out + Bb * Tt * HIDh;
  float* outp = (float*)d_ws;   // B*F*T*H

  hipLaunchKernelGGL(k_gruproj, dim3(Bb * (Ff / 8)), dim3(256), 0, stream,
                     x, Wp, bp, W_ih, b_ih, W_hh, b_hh, outp);
  hipLaunchKernelGGL(k_mha_outproj, dim3(1152), dim3(256), 0, stream,
                     outp, in_w, in_b, ow, ob, Wout, bout, attn, y);
}

// Round 9
// 56.890 us; speedup vs baseline: 1.3538x; 1.1511x over previous
//
#include <hip/hip_runtime.h>

// MHAGRU, 2 kernels: [input_proj + GRU + MHA fused, h LDS-resident] -> [out_proj].
// B=32 T=64 F=128 H=8 NH=4 HD=2 HID=32. All f32.
// d_out = [ y (B*T*HID) | attention (B*T*F*H) ]
// d_ws  = [ out (B*F,T,H) ]  (8 MB, written by K1, read only by K2)
//
// R9: MHA consumes h directly from LDS (no global round-trip on the critical
// path); outp burst-written only for the out_proj kernel. All R8 wins kept:
// component-split kv (conflict-free b128 broadcast), burst attn store,
// rcp/exp2 math. setprio(1) around the 1-wave GRU scan.

namespace {
constexpr int Bb = 32, Tt = 64, Ff = 128, Hh = 8, HIDh = 32;
constexpr int G3H = 24;
constexpr float L2E = 1.44269504088896340736f;
// K1 LDS (floats), phased overlays:
//  phase A: xs [0,8320) stride 130; xp [8320,8840)
//  phase B: hout [0,4160) (overlays xs); xp read
//  phase C: hout; OCT [4160,9280) (xp dead); WKV [9280,16192) 1728/wave
constexpr int XS_STRIDE = 130;
constexpr int XP = 8320;
constexpr int OCT = 4160;                 // o8 staging [8 f][64 t][10]
constexpr int WKV = 9280;                 // per-wave kv/q region
constexpr int KK0 = 0, KK1 = 272, VV0 = 544, VV1 = 816, QS = 1088;  // within WKV
constexpr int SM_SIZE = 16192;            // 64.8 KB -> 2 blocks/CU
}

__device__ __forceinline__ float rcp_(float x) {
#if __has_builtin(__builtin_amdgcn_rcpf)
  return __builtin_amdgcn_rcpf(x);
#else
  return 1.0f / x;
#endif
}
__device__ __forceinline__ float exp2_(float x) {
#if __has_builtin(__builtin_amdgcn_exp2f)
  return __builtin_amdgcn_exp2f(x);
#else
  return exp2f(x);
#endif
}

// 4-row softmax+PV step per kv component (R6/R8 proven)
#define MHA_STEP(K0C, K1C, V0C, V1C)                         \
  {                                                          \
    _Pragma("unroll") for (int i = 0; i < 4; ++i) {          \
      float s = fmaf(q0[i], K0C, q1[i] * K1C);               \
      float p = exp2_(s);                                    \
      ps[i] += p;                                            \
      c0[i] = fmaf(p, V0C, c0[i]);                           \
      c1[i] = fmaf(p, V1C, c1[i]);                           \
    }                                                        \
  }

// ---------------- K1: input_proj + GRU + MHA, one block per (b, 8f) ----------------
// grid: B*(F/8) = 512 blocks, 256 threads = 4 waves.
__global__ __launch_bounds__(256, 2) void k_fused(
    const float* __restrict__ x, const float* __restrict__ Wp, const float* __restrict__ bp,
    const float* __restrict__ W_ih, const float* __restrict__ b_ih,
    const float* __restrict__ W_hh, const float* __restrict__ b_hh,
    const float* __restrict__ in_w, const float* __restrict__ in_b,
    const float* __restrict__ ow, const float* __restrict__ ob,
    float* __restrict__ outp, float* __restrict__ attn) {
  __shared__ float smem[SM_SIZE];
  const int tid = threadIdx.x;
  const int blk = blockIdx.x;
  const int b = blk >> 4;
  const int f0 = (blk & 15) * 8;
  const int lane = tid & 63;
  const int w = tid >> 6;

  // ---- phase A: stage x[b] (64x128); compute xp for this block's 8 f's ----
  {
    const float2* xb = (const float2*)(x + b * Tt * Ff);
    for (int i = tid; i < Tt * Ff / 2; i += 256) {
      int row = i >> 6, col2 = i & 63;
      *(float2*)&smem[row * XS_STRIDE + col2 * 2] = xb[i];
    }
  }
  __syncthreads();
  {
    const int t = lane;
    const int fA = f0 + w, fB = f0 + w + 4;  // wave-uniform -> scalar Wp loads
    float acc0 = bp[fA], acc1 = bp[fB];
    const float* wA = Wp + fA * Ff;
    const float* wB = Wp + fB * Ff;
    const float* xr = &smem[t * XS_STRIDE];
#pragma unroll 8
    for (int k = 0; k < Ff; k += 2) {
      float2 xv = *(const float2*)&xr[k];
      acc0 = fmaf(xv.x, wA[k], acc0); acc0 = fmaf(xv.y, wA[k + 1], acc0);
      acc1 = fmaf(xv.x, wB[k], acc1); acc1 = fmaf(xv.y, wB[k + 1], acc1);
    }
    smem[XP + w * 65 + t] = acc0;
    smem[XP + (w + 4) * 65 + t] = acc1;
  }
  __syncthreads();   // xp ready; xs region dead -> hout overlays it

  // ---- phase B: GRU scan over T, wave 0 only; h -> LDS ----
  if (tid < 64) {
    __builtin_amdgcn_s_setprio(1);
    const int g = tid >> 3, j = tid & 7;
    const int f = f0 + g;
    const float* wb = W_hh + (f * G3H + j) * Hh;
    const float nL = -L2E, S2 = 2.0f * L2E;
    float w0s[8], w1s[8], w2s[8];
#pragma unroll
    for (int h = 0; h < 8; ++h) {
      w0s[h] = wb[h] * nL;
      w1s[h] = wb[64 + h] * nL;
      w2s[h] = wb[128 + h] * S2;
    }
    const float wi0s = W_ih[f * G3H + j] * nL;
    const float wi1s = W_ih[f * G3H + 8 + j] * nL;
    const float wi2s = W_ih[f * G3H + 16 + j] * S2;
    const float bias_r = (b_ih[f * G3H + j] + b_hh[f * G3H + j]) * nL;
    const float bias_z = (b_ih[f * G3H + 8 + j] + b_hh[f * G3H + 8 + j]) * nL;
    const float bi2s = b_ih[f * G3H + 16 + j] * S2;
    const float bh2s = b_hh[f * G3H + 16 + j] * S2;
    float hall[8];
#pragma unroll
    for (int h = 0; h < 8; ++h) hall[h] = 0.f;
    const int base = tid & 56;
    float* hdst = &smem[g * 520 + j * 65];   // hout[g][j][t]
    const float* xps = &smem[XP + g * 65];
    for (int t = 0; t < Tt; ++t) {
      float xt = xps[t];
      float a0 = bias_r, a1 = bias_z, a2 = bh2s;
#pragma unroll
      for (int h = 0; h < 8; ++h) {
        a0 = fmaf(hall[h], w0s[h], a0);
        a1 = fmaf(hall[h], w1s[h], a1);
        a2 = fmaf(hall[h], w2s[h], a2);
      }
      float r = rcp_(1.0f + exp2_(fmaf(xt, wi0s, a0)));
      float z = rcp_(1.0f + exp2_(fmaf(xt, wi1s, a1)));
      float narg = fmaf(r, a2, fmaf(xt, wi2s, bi2s));
      float n = fmaf(-2.0f, rcp_(exp2_(narg) + 1.0f), 1.0f);  // tanh
      float hn = fmaf(z, hall[j] - n, n);
      hdst[t] = hn;
#pragma unroll
      for (int h = 0; h < 8; ++h) hall[h] = __shfl(hn, base + h, 64);
    }
    __builtin_amdgcn_s_setprio(0);
  }
  __syncthreads();   // hout ready for all waves

  // ---- burst-write h tile to global (for out_proj kernel): 16KB contiguous ----
  {
    float4* og = (float4*)(outp + (b * Ff + f0) * Tt * Hh);
#pragma unroll
    for (int i = 0; i < 4; ++i) {
      int v = i * 256 + tid;           // float4 index within the tile (1024 total)
      int g = v >> 7;                  // f_local
      int rem = v & 127;
      int t = rem >> 1, j0 = (rem & 1) * 4;
      const float* hp = &smem[g * 520 + j0 * 65 + t];
      og[v] = make_float4(hp[0], hp[65], hp[130], hp[195]);
    }
  }

  // ---- phase C: MHA; wave w handles f_local = w and w+4, fully wave-private ----
  {
    const int t = lane;
    float* sm = &smem[WKV + w * 1728];
    constexpr float SCL = 0.70710678118654752f * L2E;
#pragma unroll
    for (int fl = w; fl < 8; fl += 4) {
      const float* hsrc = &smem[fl * 520];
      // C1: qkv projection from LDS-resident h (conflict-free: h*65+t)
      float sq[8];
#pragma unroll
      for (int h = 0; h < 8; ++h) sq[h] = hsrc[h * 65 + t];
      float qv[8], ka[8], va[8];
#pragma unroll
      for (int jj = 0; jj < 8; ++jj) {
        float aq = in_b[jj], ak = in_b[8 + jj], av = in_b[16 + jj];
#pragma unroll
        for (int h = 0; h < 8; ++h) {
          aq = fmaf(sq[h], in_w[jj * 8 + h], aq);
          ak = fmaf(sq[h], in_w[(8 + jj) * 8 + h], ak);
          av = fmaf(sq[h], in_w[(16 + jj) * 8 + h], av);
        }
        qv[jj] = aq * SCL; ka[jj] = ak; va[jj] = av;
      }
#pragma unroll
      for (int n = 0; n < 4; ++n) {
        *(float2*)&sm[QS + t * 10 + 2 * n] = make_float2(qv[2 * n], qv[2 * n + 1]);
        sm[KK0 + n * 68 + t] = ka[2 * n];
        sm[KK1 + n * 68 + t] = ka[2 * n + 1];
        sm[VV0 + n * 68 + t] = va[2 * n];
        sm[VV1 + n * 68 + t] = va[2 * n + 1];
      }
      asm volatile("s_waitcnt lgkmcnt(0)" ::: "memory");  // within-wave RAW

      // C2: lane = (n = t>>4, qq = t&15); 4 q-rows x 1 head
      const int n = t >> 4, qq = t & 15;
      float q0[4], q1[4];
#pragma unroll
      for (int i = 0; i < 4; ++i) {
        float2 qp = *(const float2*)&sm[QS + (qq + 16 * i) * 10 + 2 * n];
        q0[i] = qp.x; q1[i] = qp.y;
      }
      float ps[4], c0[4], c1[4];
#pragma unroll
      for (int i = 0; i < 4; ++i) { ps[i] = 0.f; c0[i] = 0.f; c1[i] = 0.f; }
#pragma unroll 2
      for (int kt4 = 0; kt4 < Tt; kt4 += 4) {
        float4 k0 = *(const float4*)&sm[KK0 + n * 68 + kt4];
        float4 k1 = *(const float4*)&sm[KK1 + n * 68 + kt4];
        float4 v0 = *(const float4*)&sm[VV0 + n * 68 + kt4];
        float4 v1 = *(const float4*)&sm[VV1 + n * 68 + kt4];
        MHA_STEP(k0.x, k1.x, v0.x, v1.x)
        MHA_STEP(k0.y, k1.y, v0.y, v1.y)
        MHA_STEP(k0.z, k1.z, v0.z, v1.z)
        MHA_STEP(k0.w, k1.w, v0.w, v1.w)
      }
#pragma unroll
      for (int i = 0; i < 4; ++i) {
        float inv = rcp_(ps[i]);
        *(float2*)&sm[QS + (qq + 16 * i) * 10 + 2 * n] =
            make_float2(c0[i] * inv, c1[i] * inv);   // overwrite q with ctx
      }
      asm volatile("s_waitcnt lgkmcnt(0)" ::: "memory");

      // C3: out_proj of ctx row t -> stage in OCT
      {
        float2 cp0 = *(const float2*)&sm[QS + t * 10 + 0];
        float2 cp1 = *(const float2*)&sm[QS + t * 10 + 2];
        float2 cp2 = *(const float2*)&sm[QS + t * 10 + 4];
        float2 cp3 = *(const float2*)&sm[QS + t * 10 + 6];
        float cx[8] = {cp0.x, cp0.y, cp1.x, cp1.y, cp2.x, cp2.y, cp3.x, cp3.y};
        float o8[8];
#pragma unroll
        for (int jj = 0; jj < 8; ++jj) {
          float a = ob[jj];
#pragma unroll
          for (int h = 0; h < 8; ++h) a = fmaf(cx[h], ow[jj * 8 + h], a);
          o8[jj] = a;
        }
        float* od = &smem[OCT + fl * 640 + t * 10];
        *(float4*)&od[0] = make_float4(o8[0], o8[1], o8[2], o8[3]);
        *(float4*)&od[4] = make_float4(o8[4], o8[5], o8[6], o8[7]);
      }
    }
  }
  __syncthreads();

  // ---- burst attn store: per t, 8f x 8h = 256B contiguous ----
  {
#pragma unroll
    for (int i = 0; i < 4; ++i) {
      int v = i * 256 + tid;            // float4 index (1024 total)
      int t = v >> 4;
      int c = v & 15;                   // f = c>>1, h0 = (c&1)*4
      const float* sp = &smem[OCT + (c >> 1) * 640 + t * 10 + (c & 1) * 4];
      float4* dst = (float4*)(attn + ((b * Tt + t) * Ff + f0) * Hh);
      dst[v & 15 ? c : c] = *(const float4*)sp;   // dst[c]
    }
  }
}

// ---------------- K2: y = out.reshape(B,T,F*H) @ Wout^T + bout ----------------
// grid: B*(T/8) = 256 blocks, 128 threads = 8 o-quads x 16 f-chunks (R2 proven).
__global__ __launch_bounds__(128) void k_outproj(
    const float* __restrict__ outp, const float* __restrict__ Wout,
    const float* __restrict__ bout, float* __restrict__ y) {
  constexpr int TT = 8;
  int blk = blockIdx.x;
  int b = blk >> 3;
  int t0 = (blk & 7) * TT;
  int tid = threadIdx.x;
  int oq = tid >> 4;
  int fc = tid & 15;
  float acc[TT][4];
#pragma unroll
  for (int tt = 0; tt < TT; ++tt)
#pragma unroll
    for (int od = 0; od < 4; ++od) acc[tt][od] = 0.f;
#pragma unroll
  for (int ff = 0; ff < 8; ++ff) {
    int f = fc * 8 + ff;
    const float4* rb = (const float4*)(outp + ((b * Ff + f) * Tt + t0) * Hh);
    float4 rv[16];
#pragma unroll
    for (int i = 0; i < 16; ++i) rv[i] = rb[i];
#pragma unroll
    for (int od = 0; od < 4; ++od) {
      int o = oq * 4 + od;
      const float4* wbp = (const float4*)(Wout + o * (Ff * Hh) + f * Hh);
      float4 wa = wbp[0], wc = wbp[1];
#pragma unroll
      for (int tt = 0; tt < TT; ++tt) {
        float4 ra = rv[tt * 2], rc = rv[tt * 2 + 1];
        float s = acc[tt][od];
        s = fmaf(ra.x, wa.x, s); s = fmaf(ra.y, wa.y, s);
        s = fmaf(ra.z, wa.z, s); s = fmaf(ra.w, wa.w, s);
        s = fmaf(rc.x, wc.x, s); s = fmaf(rc.y, wc.y, s);
        s = fmaf(rc.z, wc.z, s); s = fmaf(rc.w, wc.w, s);
        acc[tt][od] = s;
      }
    }
  }
#pragma unroll
  for (int tt = 0; tt < TT; ++tt)
#pragma unroll
    for (int od = 0; od < 4; ++od) {
      float v = acc[tt][od];
      v += __shfl_xor(v, 1, 16);
      v += __shfl_xor(v, 2, 16);
      v += __shfl_xor(v, 4, 16);
      v += __shfl_xor(v, 8, 16);
      acc[tt][od] = v;
    }
#pragma unroll
  for (int tt = 0; tt < TT; ++tt) {
    if (fc == tt) {
#pragma unroll
      for (int od = 0; od < 4; ++od) {
        int o = oq * 4 + od;
        y[(b * Tt + t0 + tt) * HIDh + o] = acc[tt][od] + bout[o];
      }
    }
  }
}

extern "C" void kernel_launch(void* const* d_in, const int* in_sizes, int n_in,
                              void* d_out, int out_size, void* d_ws, size_t ws_size,
                              hipStream_t stream) {
  (void)in_sizes; (void)n_in; (void)out_size; (void)ws_size;
  const float* x    = (const float*)d_in[0];
  const float* Wp   = (const float*)d_in[1];
  const float* bp   = (const float*)d_in[2];
  const float* W_ih = (const float*)d_in[3];
  const float* b_ih = (const float*)d_in[4];
  const float* W_hh = (const float*)d_in[5];
  const float* b_hh = (const float*)d_in[6];
  const float* in_w = (const float*)d_in[7];
  const float* in_b = (const float*)d_in[8];
  const float* ow   = (const float*)d_in[9];
  const float* ob   = (const float*)d_in[10];
  const float* Wout = (const float*)d_in[11];
  const float* bout = (const float*)d_in[12];

  float* y    = (float*)d_out;
  float* attn = (float*)d_out + Bb * Tt * HIDh;
  float* outp = (float*)d_ws;   // B*F*T*H

  hipLaunchKernelGGL(k_fused, dim3(Bb * (Ff / 8)), dim3(256), 0, stream,
                     x, Wp, bp, W_ih, b_ih, W_hh, b_hh, in_w, in_b, ow, ob, outp, attn);
  hipLaunchKernelGGL(k_outproj, dim3(Bb * (Tt / 8)), dim3(128), 0, stream,
                     outp, Wout, bout, y);
}